// Round 1
// baseline (96.405 us; speedup 1.0000x reference)
//
#include <hip/hip_runtime.h>

#define GAMMA 0.7f
static constexpr int K = 8;

// ---------------------------------------------------------------------------
// ws layout (host-computable offsets only):
//   [0, nblocks*K*4)            : per-block partial sums (float), written
//                                 unconditionally every call -> no zeroing
//   [countsOff, countsOff+M*4)  : per-molecule counts (int), zeroed each call
// ---------------------------------------------------------------------------

__global__ void zero_counts_kernel(int* __restrict__ counts,
                                   const int* __restrict__ Mptr) {
    int M = *Mptr;
    for (int i = blockIdx.x * blockDim.x + threadIdx.x; i < M;
         i += gridDim.x * blockDim.x)
        counts[i] = 0;
}

// Sorted ids: aggregate runs inside each int4 -> ~1 atomic per 4 atoms.
__global__ void count_kernel(const int* __restrict__ mol, int n4, int N,
                             int* __restrict__ counts) {
    int t = blockIdx.x * blockDim.x + threadIdx.x;
    if (t < n4) {
        int4 v = reinterpret_cast<const int4*>(mol)[t];
        int ids[4] = {v.x, v.y, v.z, v.w};
        int cur = ids[0], c = 1;
#pragma unroll
        for (int j = 1; j < 4; ++j) {
            if (ids[j] == cur) {
                ++c;
            } else {
                atomicAdd(&counts[cur], c);
                cur = ids[j];
                c = 1;
            }
        }
        atomicAdd(&counts[cur], c);
    }
    // tail (N not multiple of 4) handled by one thread
    if (t == 0) {
        for (int n = n4 * 4; n < N; ++n) atomicAdd(&counts[mol[n]], 1);
    }
}

// Each thread: 4 consecutive atoms, float4-vectorized loads.
// acc[k] += sq(k, atom) / count[mol(atom)], then deterministic block reduce.
__global__ void __launch_bounds__(256)
main_kernel(const float* __restrict__ sx,      // (K, N, 3)
            const float* __restrict__ xt,      // (N, 3)
            const int* __restrict__ mol,       // (N,)
            const int* __restrict__ counts,    // (M,)
            float* __restrict__ partials,      // (nblocks, K)
            int N) {
    const int t  = blockIdx.x * blockDim.x + threadIdx.x;
    const int n0 = t * 4;

    float acc[K];
#pragma unroll
    for (int k = 0; k < K; ++k) acc[k] = 0.0f;

    if (n0 + 3 < N) {
        // target coords for 4 atoms: 12 floats = 3 float4
        const float4* tp = reinterpret_cast<const float4*>(xt + (size_t)n0 * 3);
        float4 t0 = tp[0], t1 = tp[1], t2 = tp[2];
        float tg[12] = {t0.x, t0.y, t0.z, t0.w, t1.x, t1.y,
                        t1.z, t1.w, t2.x, t2.y, t2.z, t2.w};

        int4 iv = *reinterpret_cast<const int4*>(mol + n0);
        int ids[4] = {iv.x, iv.y, iv.z, iv.w};
        float inv[4];
#pragma unroll
        for (int j = 0; j < 4; ++j)
            inv[j] = 1.0f / (float)counts[ids[j]];  // count >= 1 (atom exists)

#pragma unroll
        for (int k = 0; k < K; ++k) {
            const float4* sp = reinterpret_cast<const float4*>(
                sx + (size_t)k * N * 3 + (size_t)n0 * 3);
            float4 s0 = sp[0], s1 = sp[1], s2 = sp[2];
            float sv[12] = {s0.x, s0.y, s0.z, s0.w, s1.x, s1.y,
                            s1.z, s1.w, s2.x, s2.y, s2.z, s2.w};
#pragma unroll
            for (int j = 0; j < 4; ++j) {
                float dx = sv[3 * j + 0] - tg[3 * j + 0];
                float dy = sv[3 * j + 1] - tg[3 * j + 1];
                float dz = sv[3 * j + 2] - tg[3 * j + 2];
                acc[k] += (dx * dx + dy * dy + dz * dz) * inv[j];
            }
        }
    } else if (n0 < N) {
        // scalar tail
        for (int n = n0; n < N; ++n) {
            int id = mol[n];
            float invc = 1.0f / (float)counts[id];
            float tx = xt[(size_t)n * 3 + 0];
            float ty = xt[(size_t)n * 3 + 1];
            float tz = xt[(size_t)n * 3 + 2];
#pragma unroll
            for (int k = 0; k < K; ++k) {
                const float* s = sx + (size_t)k * N * 3 + (size_t)n * 3;
                float dx = s[0] - tx, dy = s[1] - ty, dz = s[2] - tz;
                acc[k] += (dx * dx + dy * dy + dz * dz) * invc;
            }
        }
    }

    // wave64 shuffle reduce, then LDS across the 4 waves
#pragma unroll
    for (int k = 0; k < K; ++k)
#pragma unroll
        for (int off = 32; off > 0; off >>= 1)
            acc[k] += __shfl_down(acc[k], off, 64);

    __shared__ float lds[4][K];
    const int wave = threadIdx.x >> 6;
    const int lane = threadIdx.x & 63;
    if (lane == 0) {
#pragma unroll
        for (int k = 0; k < K; ++k) lds[wave][k] = acc[k];
    }
    __syncthreads();
    if (threadIdx.x < K) {
        int k = threadIdx.x;
        partials[(size_t)blockIdx.x * K + k] =
            lds[0][k] + lds[1][k] + lds[2][k] + lds[3][k];
    }
}

// One block: valid-molecule count + partial-sum reduction + weights.
__global__ void __launch_bounds__(256)
final_kernel(const float* __restrict__ partials, int nblocks,
             const int* __restrict__ counts, const int* __restrict__ Mptr,
             float* __restrict__ out) {
    const int t = threadIdx.x;
    const int M = *Mptr;

    // count valid molecules
    int vc = 0;
    for (int m = t; m < M; m += 256) vc += (counts[m] > 0) ? 1 : 0;
#pragma unroll
    for (int off = 32; off > 0; off >>= 1) vc += __shfl_down(vc, off, 64);

    // reduce per-block partials
    float acc[K];
#pragma unroll
    for (int k = 0; k < K; ++k) acc[k] = 0.0f;
    for (int i = t; i < nblocks; i += 256) {
#pragma unroll
        for (int k = 0; k < K; ++k) acc[k] += partials[(size_t)i * K + k];
    }
#pragma unroll
    for (int k = 0; k < K; ++k)
#pragma unroll
        for (int off = 32; off > 0; off >>= 1)
            acc[k] += __shfl_down(acc[k], off, 64);

    __shared__ int vlds[4];
    __shared__ float plds[4][K];
    const int wave = t >> 6, lane = t & 63;
    if (lane == 0) {
        vlds[wave] = vc;
#pragma unroll
        for (int k = 0; k < K; ++k) plds[wave][k] = acc[k];
    }
    __syncthreads();

    if (t == 0) {
        int V = vlds[0] + vlds[1] + vlds[2] + vlds[3];
        float w[K], wsum = 0.0f;
        float g = 1.0f;
        // w[K-1-j] = GAMMA^j
        for (int j = 0; j < K; ++j) {
            w[K - 1 - j] = g;
            wsum += g;
            g *= GAMMA;
        }
        float invV = (V > 0) ? 1.0f / (float)V : 0.0f;
        float res = 0.0f;
#pragma unroll
        for (int k = 0; k < K; ++k) {
            float ps = (plds[0][k] + plds[1][k] + plds[2][k] + plds[3][k]) * invV;
            res += (w[k] / wsum) * ps;
        }
        out[0] = res;
    }
}

extern "C" void kernel_launch(void* const* d_in, const int* in_sizes, int n_in,
                              void* d_out, int out_size, void* d_ws, size_t ws_size,
                              hipStream_t stream) {
    const float* states_x = (const float*)d_in[0];  // (K, N, 3)
    const float* x_target = (const float*)d_in[1];  // (N, 3)
    const int*   mol      = (const int*)d_in[2];    // (N,)
    const int*   Mptr     = (const int*)d_in[3];    // scalar on device

    const int N = in_sizes[2];
    const int n4 = N / 4;

    const int threads_main = (N + 3) / 4;
    const int nblocks = (threads_main + 255) / 256;

    // ws layout
    float* partials = (float*)d_ws;
    size_t countsOff = (((size_t)nblocks * K * 4 + 255) / 256) * 256;
    int* counts = (int*)((char*)d_ws + countsOff);

    zero_counts_kernel<<<64, 256, 0, stream>>>(counts, Mptr);

    const int cblocks = (n4 + 255) / 256;
    count_kernel<<<cblocks > 0 ? cblocks : 1, 256, 0, stream>>>(mol, n4, N, counts);

    main_kernel<<<nblocks, 256, 0, stream>>>(states_x, x_target, mol, counts,
                                             partials, N);

    final_kernel<<<1, 256, 0, stream>>>(partials, nblocks, counts, Mptr,
                                        (float*)d_out);
}